// Round 2
// baseline (460.887 us; speedup 1.0000x reference)
//
#include <hip/hip_runtime.h>
#include <hip/hip_bf16.h>

typedef unsigned short ushortT;
typedef __bf16 bf16x8 __attribute__((ext_vector_type(8)));
typedef float f32x4 __attribute__((ext_vector_type(4)));

#define OUT_SCALE 0.001f
#define RSQRT2 0.7071067811865476f

__device__ __forceinline__ float gelu_exact(float y) {
    return 0.5f * y * (1.0f + erff(y * RSQRT2));
}
__device__ __forceinline__ ushortT f2bf(float f) {
    __hip_bfloat16 h = __float2bfloat16(f);
    return *reinterpret_cast<ushortT*>(&h);
}

// ---------------------------------------------------------------------------
// K1: x path. gelu(x + dwconv3x3(x) + b), written transposed+padded as bf16:
// XgT[b][r][g=c>>5][t=col+8 (112, zero pad t<8,t>=104)][c&31]
// grid (96, 64), 384 threads: thread = (cq=tid/96, col=tid%96), 16 channels each
// ---------------------------------------------------------------------------
__global__ __launch_bounds__(384) void k_gelu_x(
    const float* __restrict__ x, const float* __restrict__ wx,
    const float* __restrict__ bx, ushortT* __restrict__ xgt)
{
    const int r   = blockIdx.x;   // image row 0..95
    const int b   = blockIdx.y;   // batch
    const int tid = threadIdx.x;
    const int cq  = tid / 96;
    const int col = tid % 96;

    __shared__ ushortT tile[7168];  // [g2][t112][c32]

    #pragma unroll 4
    for (int k = 0; k < 16; ++k) {
        const int c = cq * 16 + k;
        const float* xc = x + (size_t)(b * 64 + c) * 96 * 96;
        const float* wp = wx + c * 9;
        float w[9];
        #pragma unroll
        for (int i = 0; i < 9; ++i) w[i] = wp[i];
        const float bias = bx[c];

        float win[3][3];
        #pragma unroll
        for (int dr = 0; dr < 3; ++dr) {
            const int rr = r + dr - 1;
            const bool rok = (rr >= 0) && (rr < 96);
            #pragma unroll
            for (int dc = 0; dc < 3; ++dc) {
                const int cc = col + dc - 1;
                const bool ok = rok && (cc >= 0) && (cc < 96);
                win[dr][dc] = ok ? xc[rr * 96 + cc] : 0.0f;
            }
        }
        float acc = bias;
        #pragma unroll
        for (int dr = 0; dr < 3; ++dr)
            #pragma unroll
            for (int dc = 0; dc < 3; ++dc)
                acc += win[dr][dc] * w[dr * 3 + dc];
        const float y = acc + win[1][1];          // residual
        const float gv = gelu_exact(y);

        const int g = c >> 5, cl = c & 31, t = col + 8;
        tile[(g * 112 + t) * 32 + cl] = f2bf(gv);
    }
    // zero-pad t in [0,8) and [104,112): 2g * 16t * 32c = 1024 entries
    // (BUGFIX R1: was tt+88 -> zeroed valid cols 88..95 and left t in
    //  [104,112) uninitialized -> NaN bf16 patterns into MFMA)
    for (int i = tid; i < 1024; i += 384) {
        const int g = i >> 9, rem = i & 511, tt = rem >> 5, cl = rem & 31;
        const int t = (tt < 8) ? tt : (tt + 96);
        tile[(g * 112 + t) * 32 + cl] = 0;
    }
    __syncthreads();
    uint4* dst = (uint4*)(xgt + (size_t)(b * 96 + r) * 7168);
    const uint4* s4 = (const uint4*)tile;
    for (int i = tid; i < 896; i += 384) dst[i] = s4[i];
}

// ---------------------------------------------------------------------------
// K2: z path. gelu(z + dwconv3x3(z) + b) written as bf16 ZB[b][v][u][c64]
// grid 64, 256 threads: thread = (c=tid>>2, q=tid&3 -> v range)
// ---------------------------------------------------------------------------
__global__ __launch_bounds__(256) void k_gelu_z(
    const float* __restrict__ z, const float* __restrict__ wz,
    const float* __restrict__ bz, ushortT* __restrict__ zbuf)
{
    const int b   = blockIdx.x;
    const int tid = threadIdx.x;
    const int c   = tid >> 2;
    const int q   = tid & 3;

    __shared__ float   zs[64 * 260];   // [c][256] stride-260 (bank spread)
    __shared__ ushortT zt[16384];      // [v][u][c64]

    {   // coalesced stage of z[b]
        const float4* src = (const float4*)(z + ((size_t)b * 64 + c) * 256 + q * 64);
        float4* dstv = (float4*)(zs + c * 260 + q * 64);
        #pragma unroll
        for (int i = 0; i < 16; ++i) dstv[i] = src[i];
    }
    __syncthreads();

    const float* wp = wz + c * 9;
    float w[9];
    #pragma unroll
    for (int i = 0; i < 9; ++i) w[i] = wp[i];
    const float bias = bz[c];
    const float* zc = zs + c * 260;

    for (int v = q * 4; v < q * 4 + 4; ++v) {
        #pragma unroll
        for (int u = 0; u < 16; ++u) {
            float acc = bias;
            #pragma unroll
            for (int dr = 0; dr < 3; ++dr) {
                const int uu = u + dr - 1;
                if (uu < 0 || uu >= 16) continue;
                #pragma unroll
                for (int dc = 0; dc < 3; ++dc) {
                    const int vv = v + dc - 1;
                    if (vv < 0 || vv >= 16) continue;
                    acc += zc[uu * 16 + vv] * w[dr * 3 + dc];
                }
            }
            const float y = acc + zc[u * 16 + v];
            zt[(v * 16 + u) * 64 + c] = f2bf(gelu_exact(y));
        }
    }
    __syncthreads();
    uint4* dst = (uint4*)(zbuf + (size_t)b * 16384);
    const uint4* s4 = (const uint4*)zt;
    for (int i = tid; i < 2048; i += 256) dst[i] = s4[i];
}

// ---------------------------------------------------------------------------
// K3: correlation. Per (b, image-row r): P[j,u] = sum_{v,c} X[c,r,j-8+v]*Z[c,u,v]
// via mfma 16x16x32 bf16: M=j (7 tiles), N=u (1 tile), K=(v,c)=1024 (32 steps).
// Z fragments held in 128 VGPRs (loaded once per block). X row double-buffered
// in LDS [g][t128][c32]. Scatter P into LDS out-accumulator (ds atomic f32),
// then global f32 atomicAdd (out pre-zeroed).
// grid 512 = 64b x 8 chunks of 12 rows, 256 threads (4 waves).
// ---------------------------------------------------------------------------
__global__ __launch_bounds__(256, 2) void k_corr(
    const ushortT* __restrict__ xgt, const ushortT* __restrict__ zbuf,
    float* __restrict__ out)
{
    const int bidx  = blockIdx.x;
    const int b     = bidx >> 3;
    const int chunk = bidx & 7;
    const int r0    = chunk * 12;
    const int tid   = threadIdx.x;
    const int wave  = tid >> 6;
    const int lane  = tid & 63;
    const int n     = lane & 15;   // u (B col / C col)
    const int q     = lane >> 4;   // quad -> k offset / C row group

    __shared__ ushortT rowbuf[2][8192];   // 2 bufs x [g2][t128][c32]
    __shared__ float   outacc[27 * 113];  // rows [r0-7, r0+19], width 113 (odd stride)

    for (int i = tid; i < 27 * 113; i += 256) outacc[i] = 0.0f;
    // zero t in [112,128) of both buffers/groups (read by tile j0=96 only)
    for (int i = tid; i < 2048; i += 256) {
        const int bufi = i >> 10, rem = i & 1023, g = rem >> 9, idx = rem & 511;
        const int t = 112 + (idx >> 5), cl = idx & 31;
        rowbuf[bufi][(g * 128 + t) * 32 + cl] = 0;
    }

    // B fragments: B[k=(v,c)][n=u] = Z[c,u,v]; lane reads ZB[v][n][c0..c0+7]
    bf16x8 bfrag[32];
    const ushortT* zb = zbuf + (size_t)b * 16384;
    #pragma unroll
    for (int s = 0; s < 32; ++s) {
        const int v  = s >> 1;
        const int c0 = (s & 1) * 32 + 8 * q;
        bfrag[s] = *(const bf16x8*)(zb + (v * 16 + n) * 64 + c0);
    }

    const ushortT* src_base = xgt + (size_t)(b * 96 + r0) * 7168;
    uint4 streg[4];

#define STAGE_LOAD(RR) do {                                                    \
        const uint4* sp_ = (const uint4*)(src_base + (size_t)(RR) * 7168);     \
        _Pragma("unroll")                                                      \
        for (int k2 = 0; k2 < 4; ++k2) {                                       \
            const int i2 = tid + k2 * 256;                                     \
            if (i2 < 896) streg[k2] = sp_[i2];                                 \
        }                                                                      \
    } while (0)
#define STAGE_STORE(BUFI) do {                                                 \
        _Pragma("unroll")                                                      \
        for (int k2 = 0; k2 < 4; ++k2) {                                       \
            const int i2 = tid + k2 * 256;                                     \
            if (i2 < 896) {                                                    \
                const int e_ = i2 * 8;                                         \
                const int g_ = (e_ >= 3584) ? 1 : 0;                           \
                const int rem_ = e_ - g_ * 3584;                               \
                *(uint4*)(&rowbuf[BUFI][g_ * 4096 + rem_]) = streg[k2];        \
            }                                                                  \
        }                                                                      \
    } while (0)

    STAGE_LOAD(0);
    STAGE_STORE(0);
    __syncthreads();

    // wave tile assignment: waves 0..2 -> tiles {2w,2w+1}, wave 3 -> tile 6
    const int j0a = (wave < 3) ? wave * 32 : 96;
    int buf = 0;
    for (int rr = 0; rr < 12; ++rr) {
        if (rr + 1 < 12) STAGE_LOAD(rr + 1);   // prefetch next row (global->reg)

        f32x4 acc0 = {0.f, 0.f, 0.f, 0.f};
        f32x4 acc1 = {0.f, 0.f, 0.f, 0.f};
        const ushortT* rb = rowbuf[buf];
        const int tb_m = j0a + n;              // j0 + m  (m = lane&15)
        #pragma unroll
        for (int s = 0; s < 32; ++s) {
            const int v = s >> 1, g = s & 1;
            const int off = (g * 128 + tb_m + v) * 32 + 8 * q;
            const bf16x8 a0 = *(const bf16x8*)(rb + off);
            acc0 = __builtin_amdgcn_mfma_f32_16x16x32_bf16(a0, bfrag[s], acc0, 0, 0, 0);
            if (wave < 3) {
                const bf16x8 a1 = *(const bf16x8*)(rb + off + 16 * 32);
                acc1 = __builtin_amdgcn_mfma_f32_16x16x32_bf16(a1, bfrag[s], acc1, 0, 0, 0);
            }
        }

        if (rr + 1 < 12) STAGE_STORE(buf ^ 1); // reg->LDS (other buffer)

        // scatter: C elem (m=q*4+reg, n) -> out row i=r+8-n, col j=j0+m
        const int ii = rr + 15 - n;            // (r-r0) + 15 - n, in [0,26]
        float* orow = outacc + ii * 113 + j0a + 4 * q;
        #pragma unroll
        for (int g3 = 0; g3 < 4; ++g3) atomicAdd(&orow[g3], acc0[g3]);
        if (wave < 3) {
            #pragma unroll
            for (int g3 = 0; g3 < 4; ++g3) atomicAdd(&orow[16 + g3], acc1[g3]);
        }
        __syncthreads();
        buf ^= 1;
    }

    // write out (rows [r0-7, r0+19], valid i in [0,97), valid j in [0,97))
    float* outb = out + (size_t)b * 9409;
    for (int i = tid; i < 27 * 97; i += 256) {
        const int ii = i / 97, j = i - ii * 97;
        const int irow = r0 - 7 + ii;
        if (irow >= 0 && irow < 97)
            atomicAdd(&outb[irow * 97 + j], outacc[ii * 113 + j] * OUT_SCALE);
    }
#undef STAGE_LOAD
#undef STAGE_STORE
}

// ---------------------------------------------------------------------------
extern "C" void kernel_launch(void* const* d_in, const int* in_sizes, int n_in,
                              void* d_out, int out_size, void* d_ws, size_t ws_size,
                              hipStream_t stream)
{
    const float* z  = (const float*)d_in[0];
    const float* x  = (const float*)d_in[1];
    const float* wz = (const float*)d_in[2];
    const float* bz = (const float*)d_in[3];
    const float* wx = (const float*)d_in[4];
    const float* bx = (const float*)d_in[5];
    float* out = (float*)d_out;

    // workspace: XgT (64*96*7168 bf16 = 88.08 MB) then ZB (64*16384 bf16 = 2 MB)
    ushortT* xgt  = (ushortT*)d_ws;
    ushortT* zbuf = (ushortT*)((char*)d_ws + (size_t)64 * 96 * 7168 * 2);

    hipMemsetAsync(d_out, 0, (size_t)out_size * 4, stream);

    k_gelu_x<<<dim3(96, 64), 384, 0, stream>>>(x, wx, bx, xgt);
    k_gelu_z<<<dim3(64), 256, 0, stream>>>(z, wz, bz, zbuf);
    k_corr<<<dim3(512), 256, 0, stream>>>(xgt, zbuf, out);

    (void)in_sizes; (void)n_in; (void)ws_size;
}

// Round 3
// 436.719 us; speedup vs baseline: 1.0553x; 1.0553x over previous
//
#include <hip/hip_runtime.h>
#include <hip/hip_bf16.h>

typedef unsigned short ushortT;
typedef __bf16 bf16x8 __attribute__((ext_vector_type(8)));
typedef float f32x4 __attribute__((ext_vector_type(4)));

#define OUT_SCALE 0.001f

// fast GELU: v * sigmoid(1.5957691*(v + 0.044715 v^3)); |err vs exact| <~1e-3
__device__ __forceinline__ float gelu_fast(float v) {
    const float u = v * fmaf(0.044715f * v, v, 1.0f);
    const float e = __expf(-1.5957691216057308f * u);
    return v * __builtin_amdgcn_rcpf(1.0f + e);
}
__device__ __forceinline__ ushortT f2bf(float f) {
    __hip_bfloat16 h = __float2bfloat16(f);
    return *reinterpret_cast<ushortT*>(&h);
}
__device__ __forceinline__ float bf2f(ushortT u) {
    union { unsigned int i; float f; } x;
    x.i = ((unsigned int)u) << 16;
    return x.f;
}

// Swizzle shared by K1 stores / K3 reads: within a 32-ushort row T, 8-elem
// chunk k is stored at chunk k ^ ((T>>1)&3). Spreads the stride-64B rows
// across bank groups (un-swizzled: 16 same-q lanes hit one 4-bank span).

// ---------------------------------------------------------------------------
// K1: x path. gelu(x + dwconv3x3(x) + b) -> XgT[b][r][g][T112][c32 swizzled]
// grid (96,64), 512 thr. Stage rows r-1..r+1 (64ch) as bf16 in LDS (coalesced
// float4 loads, zero halos), then thread=(c, 12-col group) register sliding.
// ---------------------------------------------------------------------------
__global__ __launch_bounds__(512) void k_gelu_x(
    const float* __restrict__ x, const float* __restrict__ wx,
    const float* __restrict__ bx, ushortT* __restrict__ xgt)
{
    const int r = blockIdx.x, b = blockIdx.y, tid = threadIdx.x;

    __shared__ ushortT xs[3][64][104];  // col j at idx j+4; zeros at [0,4) & [100,104)
    __shared__ ushortT tile[7168];      // [g2][T112][c32] (chunk-swizzled)

    // stage 3 rows (bf16), coalesced float4: 3*64*24 = 4608 float4 = 512*9
    #pragma unroll
    for (int k = 0; k < 9; ++k) {
        const int idx = tid + k * 512;
        const int dr = idx / 1536, rem = idx - dr * 1536;
        const int c = rem / 24, f4 = rem - c * 24;
        const int rr = r + dr - 1;
        float4 v = make_float4(0.f, 0.f, 0.f, 0.f);
        if (rr >= 0 && rr < 96)
            v = *(const float4*)(x + ((size_t)(b * 64 + c) * 96 + rr) * 96 + 4 * f4);
        ushort4 o;
        o.x = f2bf(v.x); o.y = f2bf(v.y); o.z = f2bf(v.z); o.w = f2bf(v.w);
        *(ushort4*)(&xs[dr][c][4 + 4 * f4]) = o;
    }
    // zero halos (cols -4..-1 and 96..99 in padded index space)
    for (int i = tid; i < 768; i += 512) {
        const int dr = i >> 8, rem = i & 255, c = rem >> 2, h = rem & 3;
        xs[dr][c][h] = 0;
        xs[dr][c][100 + h] = 0;
    }
    // zero tile pad rows T in [0,8) and [104,112)
    for (int i = tid; i < 1024; i += 512) {
        const int g = i >> 9, rem = i & 511, tt = rem >> 5, cl = rem & 31;
        const int T = (tt < 8) ? tt : (tt + 96);
        tile[(g * 112 + T) * 32 + cl] = 0;
    }
    __syncthreads();

    // compute: thread = (c, colg); cols [12*colg, 12*colg+12)
    const int c = tid >> 3, colg = tid & 7, j0 = colg * 12;
    const float* wp = wx + c * 9;
    float w[9];
    #pragma unroll
    for (int i = 0; i < 9; ++i) w[i] = wp[i];
    const float bias = bx[c];

    float win[3][14];
    #pragma unroll
    for (int dr = 0; dr < 3; ++dr)
        #pragma unroll
        for (int k = 0; k < 14; ++k)
            win[dr][k] = bf2f(xs[dr][c][j0 + 3 + k]);  // col j0-1+k

    const int g = c >> 5, cl = c & 31, chunk = cl >> 3, pos = cl & 7;
    #pragma unroll
    for (int jj = 0; jj < 12; ++jj) {
        float acc = bias;
        #pragma unroll
        for (int dr = 0; dr < 3; ++dr)
            acc += win[dr][jj] * w[dr * 3] + win[dr][jj + 1] * w[dr * 3 + 1]
                 + win[dr][jj + 2] * w[dr * 3 + 2];
        const float y = acc + win[1][jj + 1];          // residual
        const int T = j0 + jj + 8;
        const int schunk = chunk ^ ((T >> 1) & 3);
        tile[(g * 112 + T) * 32 + schunk * 8 + pos] = f2bf(gelu_fast(y));
    }
    __syncthreads();

    uint4* dst = (uint4*)(xgt + (size_t)(b * 96 + r) * 7168);
    const uint4* s4 = (const uint4*)tile;
    for (int i = tid; i < 896; i += 512) dst[i] = s4[i];
}

// ---------------------------------------------------------------------------
// K2: z path. gelu(z + dwconv3x3(z) + b) written as bf16 ZB[b][v][u][c64]
// ---------------------------------------------------------------------------
__global__ __launch_bounds__(256) void k_gelu_z(
    const float* __restrict__ z, const float* __restrict__ wz,
    const float* __restrict__ bz, ushortT* __restrict__ zbuf)
{
    const int b   = blockIdx.x;
    const int tid = threadIdx.x;
    const int c   = tid >> 2;
    const int q   = tid & 3;

    __shared__ float   zs[64 * 260];
    __shared__ ushortT zt[16384];

    {
        const float4* src = (const float4*)(z + ((size_t)b * 64 + c) * 256 + q * 64);
        float4* dstv = (float4*)(zs + c * 260 + q * 64);
        #pragma unroll
        for (int i = 0; i < 16; ++i) dstv[i] = src[i];
    }
    __syncthreads();

    const float* wp = wz + c * 9;
    float w[9];
    #pragma unroll
    for (int i = 0; i < 9; ++i) w[i] = wp[i];
    const float bias = bz[c];
    const float* zc = zs + c * 260;

    for (int v = q * 4; v < q * 4 + 4; ++v) {
        #pragma unroll
        for (int u = 0; u < 16; ++u) {
            float acc = bias;
            #pragma unroll
            for (int dr = 0; dr < 3; ++dr) {
                const int uu = u + dr - 1;
                if (uu < 0 || uu >= 16) continue;
                #pragma unroll
                for (int dc = 0; dc < 3; ++dc) {
                    const int vv = v + dc - 1;
                    if (vv < 0 || vv >= 16) continue;
                    acc += zc[uu * 16 + vv] * w[dr * 3 + dc];
                }
            }
            const float y = acc + zc[u * 16 + v];
            zt[(v * 16 + u) * 64 + c] = f2bf(gelu_fast(y));
        }
    }
    __syncthreads();
    uint4* dst = (uint4*)(zbuf + (size_t)b * 16384);
    const uint4* s4 = (const uint4*)zt;
    for (int i = tid; i < 2048; i += 256) dst[i] = s4[i];
}

// ---------------------------------------------------------------------------
// K3: correlation via mfma 16x16x32 bf16. A-reads use the chunk swizzle
// (matches K1's stores; STAGE copy is linear so global layout carries it).
// ---------------------------------------------------------------------------
__global__ __launch_bounds__(256, 2) void k_corr(
    const ushortT* __restrict__ xgt, const ushortT* __restrict__ zbuf,
    float* __restrict__ out)
{
    const int bidx  = blockIdx.x;
    const int b     = bidx >> 3;
    const int chunk = bidx & 7;
    const int r0    = chunk * 12;
    const int tid   = threadIdx.x;
    const int wave  = tid >> 6;
    const int lane  = tid & 63;
    const int n     = lane & 15;   // u
    const int q     = lane >> 4;   // k-chunk

    __shared__ ushortT rowbuf[2][8192];   // 2 x [g2][T128][c32 swizzled]
    __shared__ float   outacc[27 * 113];

    for (int i = tid; i < 27 * 113; i += 256) outacc[i] = 0.0f;
    for (int i = tid; i < 2048; i += 256) {   // zero rows T in [112,128)
        const int bufi = i >> 10, rem = i & 1023, g = rem >> 9, idx = rem & 511;
        const int T = 112 + (idx >> 5), cl = idx & 31;
        rowbuf[bufi][(g * 128 + T) * 32 + cl] = 0;
    }

    bf16x8 bfrag[32];
    const ushortT* zb = zbuf + (size_t)b * 16384;
    #pragma unroll
    for (int s = 0; s < 32; ++s) {
        const int v  = s >> 1;
        const int c0 = (s & 1) * 32 + 8 * q;
        bfrag[s] = *(const bf16x8*)(zb + (v * 16 + n) * 64 + c0);
    }

    const ushortT* src_base = xgt + (size_t)(b * 96 + r0) * 7168;
    uint4 streg[4];

#define STAGE_LOAD(RR) do {                                                    \
        const uint4* sp_ = (const uint4*)(src_base + (size_t)(RR) * 7168);     \
        _Pragma("unroll")                                                      \
        for (int k2 = 0; k2 < 4; ++k2) {                                       \
            const int i2 = tid + k2 * 256;                                     \
            if (i2 < 896) streg[k2] = sp_[i2];                                 \
        }                                                                      \
    } while (0)
#define STAGE_STORE(BUFI) do {                                                 \
        _Pragma("unroll")                                                      \
        for (int k2 = 0; k2 < 4; ++k2) {                                       \
            const int i2 = tid + k2 * 256;                                     \
            if (i2 < 896) {                                                    \
                const int e_ = i2 * 8;                                         \
                const int g_ = (e_ >= 3584) ? 1 : 0;                           \
                const int rem_ = e_ - g_ * 3584;                               \
                *(uint4*)(&rowbuf[BUFI][g_ * 4096 + rem_]) = streg[k2];        \
            }                                                                  \
        }                                                                      \
    } while (0)

    STAGE_LOAD(0);
    STAGE_STORE(0);
    __syncthreads();

    const int j0a = (wave < 3) ? wave * 32 : 96;
    int buf = 0;
    for (int rr = 0; rr < 12; ++rr) {
        if (rr + 1 < 12) STAGE_LOAD(rr + 1);

        f32x4 acc0 = {0.f, 0.f, 0.f, 0.f};
        f32x4 acc1 = {0.f, 0.f, 0.f, 0.f};
        const ushortT* rb = rowbuf[buf];
        const int tb_m = j0a + n;
        #pragma unroll
        for (int s = 0; s < 32; ++s) {
            const int v = s >> 1, g = s & 1;
            const int T = tb_m + v;
            const int schunk = q ^ ((T >> 1) & 3);
            const int off = (g * 128 + T) * 32 + schunk * 8;
            const bf16x8 a0 = *(const bf16x8*)(rb + off);
            acc0 = __builtin_amdgcn_mfma_f32_16x16x32_bf16(a0, bfrag[s], acc0, 0, 0, 0);
            if (wave < 3) {
                // T+16: (T>>1)&3 unchanged (+8 == 0 mod 4) -> same swizzle
                const bf16x8 a1 = *(const bf16x8*)(rb + off + 16 * 32);
                acc1 = __builtin_amdgcn_mfma_f32_16x16x32_bf16(a1, bfrag[s], acc1, 0, 0, 0);
            }
        }

        if (rr + 1 < 12) STAGE_STORE(buf ^ 1);

        const int ii = rr + 15 - n;
        float* orow = outacc + ii * 113 + j0a + 4 * q;
        #pragma unroll
        for (int g3 = 0; g3 < 4; ++g3) atomicAdd(&orow[g3], acc0[g3]);
        if (wave < 3) {
            #pragma unroll
            for (int g3 = 0; g3 < 4; ++g3) atomicAdd(&orow[16 + g3], acc1[g3]);
        }
        __syncthreads();
        buf ^= 1;
    }

    float* outb = out + (size_t)b * 9409;
    for (int i = tid; i < 27 * 97; i += 256) {
        const int ii = i / 97, j = i - ii * 97;
        const int irow = r0 - 7 + ii;
        if (irow >= 0 && irow < 97)
            atomicAdd(&outb[irow * 97 + j], outacc[ii * 113 + j] * OUT_SCALE);
    }
#undef STAGE_LOAD
#undef STAGE_STORE
}

// ---------------------------------------------------------------------------
extern "C" void kernel_launch(void* const* d_in, const int* in_sizes, int n_in,
                              void* d_out, int out_size, void* d_ws, size_t ws_size,
                              hipStream_t stream)
{
    const float* z  = (const float*)d_in[0];
    const float* x  = (const float*)d_in[1];
    const float* wz = (const float*)d_in[2];
    const float* bz = (const float*)d_in[3];
    const float* wx = (const float*)d_in[4];
    const float* bx = (const float*)d_in[5];
    float* out = (float*)d_out;

    ushortT* xgt  = (ushortT*)d_ws;
    ushortT* zbuf = (ushortT*)((char*)d_ws + (size_t)64 * 96 * 7168 * 2);

    hipMemsetAsync(d_out, 0, (size_t)out_size * 4, stream);

    k_gelu_x<<<dim3(96, 64), 512, 0, stream>>>(x, wx, bx, xgt);
    k_gelu_z<<<dim3(64), 256, 0, stream>>>(z, wz, bz, zbuf);
    k_corr<<<dim3(512), 256, 0, stream>>>(xgt, zbuf, out);

    (void)in_sizes; (void)n_in; (void)ws_size;
}